// Round 2
// baseline (399.051 us; speedup 1.0000x reference)
//
#include <hip/hip_runtime.h>
#include <math.h>

// Problem constants
#define NB 32     // batch
#define NC 256    // channels
#define NT 512    // time
#define NH 8      // heads
#define ND 32     // head dim
#define SCALE 0.17677669529663687f   // 1/sqrt(32)

// =====================================================================
// Kernel 1: fused QKV projection.
//   Q[b,h,t,j] = relu( bq[c] + sum_ci seq[b,ci,t] * Wq[c,ci] ),  c = h*32+j
// Block: 64 t  x 64 co tile for ONE batch, all three projections.
// 256 threads, 4x4 register tile per thread per projection.
// =====================================================================
__global__ __launch_bounds__(256) void qkv_kernel(
    const float* __restrict__ seq,
    const float* __restrict__ Wq, const float* __restrict__ bq,
    const float* __restrict__ Wk, const float* __restrict__ bk,
    const float* __restrict__ Wv, const float* __restrict__ bv,
    float* __restrict__ Qh, float* __restrict__ Kh, float* __restrict__ Vh)
{
    __shared__ float As[16][64];        // [c-chunk][t]
    __shared__ float Ws[3][16][64];     // [proj][c-chunk][co]

    const int tid = threadIdx.x;
    const int t0  = blockIdx.x * 64;
    const int co0 = blockIdx.y * 64;
    const int bb  = blockIdx.z;

    const float* Wp[3] = {Wq, Wk, Wv};

    float acc[3][4][4];
    #pragma unroll
    for (int p = 0; p < 3; ++p)
        #pragma unroll
        for (int i = 0; i < 4; ++i)
            #pragma unroll
            for (int j = 0; j < 4; ++j) acc[p][i][j] = 0.f;

    const int ty = tid >> 4;        // 0..15 : t-group (4 rows)
    const int tx = tid & 15;        // 0..15 : co-group (4 cols)

    const int a_cc = tid >> 4;          // 0..15
    const int a_t4 = (tid & 15) * 4;    // 0..60
    const int w_co = tid >> 2;          // 0..63
    const int w_c4 = (tid & 3) * 4;     // 0..12

    for (int c0 = 0; c0 < NC; c0 += 16) {
        // prefetch to registers
        const float4 av = *(const float4*)&seq[((size_t)(bb*NC + c0 + a_cc))*NT + t0 + a_t4];
        float4 wv[3];
        #pragma unroll
        for (int p = 0; p < 3; ++p)
            wv[p] = *(const float4*)&Wp[p][(size_t)(co0 + w_co)*NC + c0 + w_c4];

        __syncthreads();   // previous iteration's compute done reading LDS
        *(float4*)&As[a_cc][a_t4] = av;
        #pragma unroll
        for (int p = 0; p < 3; ++p) {
            Ws[p][w_c4+0][w_co] = wv[p].x;
            Ws[p][w_c4+1][w_co] = wv[p].y;
            Ws[p][w_c4+2][w_co] = wv[p].z;
            Ws[p][w_c4+3][w_co] = wv[p].w;
        }
        __syncthreads();

        #pragma unroll
        for (int cc = 0; cc < 16; ++cc) {
            const float4 a4 = *(const float4*)&As[cc][ty*4];
            const float a[4] = {a4.x, a4.y, a4.z, a4.w};
            #pragma unroll
            for (int p = 0; p < 3; ++p) {
                const float4 w4 = *(const float4*)&Ws[p][cc][tx*4];
                const float w[4] = {w4.x, w4.y, w4.z, w4.w};
                #pragma unroll
                for (int i = 0; i < 4; ++i)
                    #pragma unroll
                    for (int j = 0; j < 4; ++j)
                        acc[p][i][j] = fmaf(a[i], w[j], acc[p][i][j]);
            }
        }
    }

    // epilogue: bias + relu, write [b,h,t,j] layout
    const float* bias[3] = {bq, bk, bv};
    float* outp[3] = {Qh, Kh, Vh};
    const int co = co0 + tx*4;
    const int hh = co >> 5;
    const int jj = co & 31;
    #pragma unroll
    for (int p = 0; p < 3; ++p) {
        const float b0 = bias[p][co+0], b1 = bias[p][co+1];
        const float b2 = bias[p][co+2], b3 = bias[p][co+3];
        #pragma unroll
        for (int i = 0; i < 4; ++i) {
            const int t = t0 + ty*4 + i;
            float4 r;
            r.x = fmaxf(acc[p][i][0] + b0, 0.f);
            r.y = fmaxf(acc[p][i][1] + b1, 0.f);
            r.z = fmaxf(acc[p][i][2] + b2, 0.f);
            r.w = fmaxf(acc[p][i][3] + b3, 0.f);
            *(float4*)&outp[p][((size_t)(bb*NH + hh)*NT + t)*ND + jj] = r;
        }
    }
}

// =====================================================================
// Kernel 2: flash-style masked attention for one (b, h, 128-row q-tile).
// s-chunks of 64, online softmax (running max m, denom l).
// Writes pre-BN x directly into out[b, c, t] (c = h*32 + j).
// =====================================================================
__global__ __launch_bounds__(256) void attn_kernel(
    const float* __restrict__ Qh, const float* __restrict__ Kh,
    const float* __restrict__ Vh, const int* __restrict__ mask,
    float* __restrict__ xout)
{
    __shared__ float QsT[32][132];   // [c][t] transposed Q tile (pad keeps 16B align)
    __shared__ float KsT[32][68];    // [c][s] transposed K chunk
    __shared__ float Vs[64][36];     // [s][j] V chunk
    __shared__ float Sb[128][68];    // [t][s] scores -> probabilities
    __shared__ int   smask[64];      // key mask chunk
    __shared__ float rowf[128];      // per-row rescale factor
    __shared__ float rowl[128];      // per-row final 1/l * qmask

    const int tid = threadIdx.x;
    const int t0  = blockIdx.x * 128;
    const int h   = blockIdx.y;
    const int bb  = blockIdx.z;
    const int bh  = bb*NH + h;
    const float* Qp = Qh + (size_t)bh*NT*ND;
    const float* Kp = Kh + (size_t)bh*NT*ND;
    const float* Vp = Vh + (size_t)bh*NT*ND;

    // stage Q transposed: 128 x 32
    #pragma unroll
    for (int r = 0; r < 4; ++r) {
        const int idx = r*256 + tid;
        const int t = idx >> 3, j4 = (idx & 7)*4;
        const float4 q = *(const float4*)&Qp[(size_t)(t0 + t)*ND + j4];
        QsT[j4+0][t] = q.x; QsT[j4+1][t] = q.y;
        QsT[j4+2][t] = q.z; QsT[j4+3][t] = q.w;
    }

    float accO[4][4];
    #pragma unroll
    for (int i = 0; i < 4; ++i)
        #pragma unroll
        for (int j = 0; j < 4; ++j) accO[i][j] = 0.f;
    float m_run = -1e30f, l_run = 0.f;

    const int tg = tid >> 3;      // 0..31 : t-group (4 rows) for QK & PV
    const int sg = tid & 7;       // 0..7  : s-group (QK) / j-group (PV)
    const int sm_row = tid >> 1;  // 0..127
    const int sm_li  = tid & 1;

    for (int s0 = 0; s0 < NT; s0 += 64) {
        __syncthreads();   // prior chunk done with KsT/Vs/Sb
        // ---- stage K (transposed), V, key-mask chunk ----
        #pragma unroll
        for (int r = 0; r < 2; ++r) {
            const int idx = r*256 + tid;
            const int ss = idx >> 3, j4 = (idx & 7)*4;
            const float4 kv = *(const float4*)&Kp[(size_t)(s0+ss)*ND + j4];
            KsT[j4+0][ss] = kv.x; KsT[j4+1][ss] = kv.y;
            KsT[j4+2][ss] = kv.z; KsT[j4+3][ss] = kv.w;
            const float4 vv = *(const float4*)&Vp[(size_t)(s0+ss)*ND + j4];
            *(float4*)&Vs[ss][j4] = vv;
        }
        if (tid < 64) smask[tid] = mask[bb*NT + s0 + tid];
        __syncthreads();

        // ---- S = Q K^T * scale, key-masked (exact -1e9 replace) ----
        {
            float sres[4][8];
            #pragma unroll
            for (int i = 0; i < 4; ++i)
                #pragma unroll
                for (int s = 0; s < 8; ++s) sres[i][s] = 0.f;
            #pragma unroll
            for (int c = 0; c < 32; ++c) {
                const float4 q4  = *(const float4*)&QsT[c][tg*4];
                const float4 k4a = *(const float4*)&KsT[c][sg*8];
                const float4 k4b = *(const float4*)&KsT[c][sg*8+4];
                const float q[4] = {q4.x, q4.y, q4.z, q4.w};
                const float k[8] = {k4a.x,k4a.y,k4a.z,k4a.w, k4b.x,k4b.y,k4b.z,k4b.w};
                #pragma unroll
                for (int i = 0; i < 4; ++i)
                    #pragma unroll
                    for (int s = 0; s < 8; ++s)
                        sres[i][s] = fmaf(q[i], k[s], sres[i][s]);
            }
            int km[8];
            #pragma unroll
            for (int s = 0; s < 8; ++s) km[s] = smask[sg*8+s];
            #pragma unroll
            for (int i = 0; i < 4; ++i) {
                float4 lo, hi;
                lo.x = km[0] ? sres[i][0]*SCALE : -1e9f;
                lo.y = km[1] ? sres[i][1]*SCALE : -1e9f;
                lo.z = km[2] ? sres[i][2]*SCALE : -1e9f;
                lo.w = km[3] ? sres[i][3]*SCALE : -1e9f;
                hi.x = km[4] ? sres[i][4]*SCALE : -1e9f;
                hi.y = km[5] ? sres[i][5]*SCALE : -1e9f;
                hi.z = km[6] ? sres[i][6]*SCALE : -1e9f;
                hi.w = km[7] ? sres[i][7]*SCALE : -1e9f;
                *(float4*)&Sb[tg*4+i][sg*8]   = lo;
                *(float4*)&Sb[tg*4+i][sg*8+4] = hi;
            }
        }
        __syncthreads();

        // ---- partial row softmax: 2 lanes per row, 32 cols each ----
        {
            float vals[32];
            float mx = -1e30f;
            #pragma unroll
            for (int k4 = 0; k4 < 8; ++k4) {
                const float4 v = *(const float4*)&Sb[sm_row][sm_li*32 + k4*4];
                vals[k4*4+0] = v.x; vals[k4*4+1] = v.y;
                vals[k4*4+2] = v.z; vals[k4*4+3] = v.w;
                mx = fmaxf(mx, fmaxf(fmaxf(v.x, v.y), fmaxf(v.z, v.w)));
            }
            mx = fmaxf(mx, __shfl_xor(mx, 1));
            const float m_new = fmaxf(m_run, mx);
            const float f = __expf(m_run - m_new);   // first chunk: exp(-inf-ish)=0
            float ssum = 0.f;
            #pragma unroll
            for (int k = 0; k < 32; ++k) {
                const float p = __expf(vals[k] - m_new);
                vals[k] = p;
                ssum += p;
            }
            #pragma unroll
            for (int k4 = 0; k4 < 8; ++k4) {
                float4 v;
                v.x = vals[k4*4+0]; v.y = vals[k4*4+1];
                v.z = vals[k4*4+2]; v.w = vals[k4*4+3];
                *(float4*)&Sb[sm_row][sm_li*32 + k4*4] = v;
            }
            ssum += __shfl_xor(ssum, 1);
            l_run = fmaf(l_run, f, ssum);
            m_run = m_new;
            if (sm_li == 0) rowf[sm_row] = f;
        }
        __syncthreads();

        // ---- accO = accO * f + P @ V ----
        {
            float fr[4];
            #pragma unroll
            for (int i = 0; i < 4; ++i) fr[i] = rowf[tg*4+i];
            #pragma unroll
            for (int i = 0; i < 4; ++i)
                #pragma unroll
                for (int j = 0; j < 4; ++j) accO[i][j] *= fr[i];

            for (int s4 = 0; s4 < 64; s4 += 4) {
                float p[4][4], v[4][4];
                #pragma unroll
                for (int i = 0; i < 4; ++i)
                    *(float4*)p[i] = *(const float4*)&Sb[tg*4+i][s4];
                #pragma unroll
                for (int k = 0; k < 4; ++k)
                    *(float4*)v[k] = *(const float4*)&Vs[s4+k][sg*4];
                #pragma unroll
                for (int i = 0; i < 4; ++i)
                    #pragma unroll
                    for (int k = 0; k < 4; ++k)
                        #pragma unroll
                        for (int j = 0; j < 4; ++j)
                            accO[i][j] = fmaf(p[i][k], v[k][j], accO[i][j]);
            }
        }
    }

    // ---- epilogue: final 1/l * query-mask, write x[b, c, t] ----
    if (sm_li == 0) {
        const int qm = mask[bb*NT + t0 + sm_row];
        rowl[sm_row] = qm ? (1.f / l_run) : 0.f;
    }
    __syncthreads();
    float rl[4];
    #pragma unroll
    for (int i = 0; i < 4; ++i) rl[i] = rowl[tg*4+i];
    #pragma unroll
    for (int j = 0; j < 4; ++j) {
        float4 o;
        o.x = accO[0][j]*rl[0];
        o.y = accO[1][j]*rl[1];
        o.z = accO[2][j]*rl[2];
        o.w = accO[3][j]*rl[3];
        *(float4*)&xout[((size_t)(bb*NC + h*ND + sg*4 + j))*NT + t0 + tg*4] = o;
    }
}

// =====================================================================
// Kernel 3: per-channel batch stats over (B,T). One block per channel.
// stats[c] = mean, stats[256+c] = 1/sqrt(var+eps)  (biased var)
// =====================================================================
__global__ __launch_bounds__(256) void bn_stats_kernel(
    const float* __restrict__ x, float* __restrict__ stats)
{
    const int c = blockIdx.x;
    const int tid = threadIdx.x;
    float s = 0.f, s2 = 0.f;
    for (int bb = 0; bb < NB; ++bb) {
        const float* p = x + ((size_t)(bb*NC + c))*NT;
        const float2 v = *(const float2*)&p[tid*2];
        s  += v.x + v.y;
        s2 += v.x*v.x + v.y*v.y;
    }
    #pragma unroll
    for (int o = 1; o < 64; o <<= 1) {
        s  += __shfl_xor(s,  o);
        s2 += __shfl_xor(s2, o);
    }
    __shared__ float red[8];
    const int w = tid >> 6;
    if ((tid & 63) == 0) { red[w] = s; red[4+w] = s2; }
    __syncthreads();
    if (tid == 0) {
        const float S  = red[0]+red[1]+red[2]+red[3];
        const float S2 = red[4]+red[5]+red[6]+red[7];
        const float mean = S * (1.f/16384.f);
        const float var  = fmaxf(S2 * (1.f/16384.f) - mean*mean, 0.f);
        stats[c]      = mean;
        stats[NC + c] = 1.f / sqrtf(var + 1e-5f);
    }
}

// =====================================================================
// Kernel 4: BN normalize + affine + re-mask, in place on d_out.
// =====================================================================
__global__ __launch_bounds__(256) void bn_apply_kernel(
    float* __restrict__ x, const float* __restrict__ stats,
    const float* __restrict__ gamma, const float* __restrict__ beta,
    const int* __restrict__ mask)
{
    const int idx = blockIdx.x*256 + threadIdx.x;   // float4 index
    const int t4 = idx & 127;
    const int c  = (idx >> 7) & 255;
    const int bb = idx >> 15;
    float4 v = ((const float4*)x)[idx];
    const int4 mk = *(const int4*)&mask[bb*NT + t4*4];
    const float mean = stats[c], rstd = stats[NC + c];
    const float g = gamma[c], be = beta[c];
    v.x = mk.x ? fmaf((v.x - mean)*rstd, g, be) : 0.f;
    v.y = mk.y ? fmaf((v.y - mean)*rstd, g, be) : 0.f;
    v.z = mk.z ? fmaf((v.z - mean)*rstd, g, be) : 0.f;
    v.w = mk.w ? fmaf((v.w - mean)*rstd, g, be) : 0.f;
    ((float4*)x)[idx] = v;
}

extern "C" void kernel_launch(void* const* d_in, const int* in_sizes, int n_in,
                              void* d_out, int out_size, void* d_ws, size_t ws_size,
                              hipStream_t stream)
{
    const float* seq   = (const float*)d_in[0];
    const int*   mask  = (const int*)  d_in[1];
    const float* Wq    = (const float*)d_in[2];
    const float* bq    = (const float*)d_in[3];
    const float* Wk    = (const float*)d_in[4];
    const float* bk    = (const float*)d_in[5];
    const float* Wv    = (const float*)d_in[6];
    const float* bv    = (const float*)d_in[7];
    const float* gamma = (const float*)d_in[8];
    const float* beta  = (const float*)d_in[9];
    float* out = (float*)d_out;

    const size_t perMat = (size_t)NB*NH*NT*ND;   // 4,194,304 floats
    float* Qh    = (float*)d_ws;
    float* Kh    = Qh + perMat;
    float* Vh    = Kh + perMat;
    float* stats = Vh + perMat;                  // 512 floats

    qkv_kernel<<<dim3(NT/64, NC/64, NB), 256, 0, stream>>>(
        seq, Wq, bq, Wk, bk, Wv, bv, Qh, Kh, Vh);
    attn_kernel<<<dim3(NT/128, NH, NB), 256, 0, stream>>>(
        Qh, Kh, Vh, mask, out);
    bn_stats_kernel<<<dim3(NC), 256, 0, stream>>>(out, stats);
    bn_apply_kernel<<<dim3((NB*NC*NT/4)/256), 256, 0, stream>>>(
        out, stats, gamma, beta, mask);
}

// Round 3
// 157.315 us; speedup vs baseline: 2.5366x; 2.5366x over previous
//
#include <hip/hip_runtime.h>
#include <math.h>

#define NB 32     // batch
#define NC 256    // channels
#define NT 512    // time
#define NH 8      // heads
#define ND 32     // head dim
#define SCALE 0.17677669529663687f   // 1/sqrt(32)

typedef __attribute__((ext_vector_type(8))) __bf16 bf16x8;
typedef __attribute__((ext_vector_type(4))) __bf16 bf16x4;
typedef __attribute__((ext_vector_type(4))) float  f32x4;

static __device__ __forceinline__ f32x4 mfma16x16x32(bf16x8 a, bf16x8 b, f32x4 c) {
    return __builtin_amdgcn_mfma_f32_16x16x32_bf16(a, b, c, 0, 0, 0);
}

// =====================================================================
// Kernel 1: fused QKV projection via bf16 MFMA.
// Block: 64 t x 64 co for one batch, all 3 projections. 256 thr = 4 waves.
// A = seq^T tile staged bf16 [64][264] (full K=256); W per-32-K chunk,
// register-prefetched. Q is pre-scaled by 1/sqrt(d).
// Outputs Q,K,V bf16 in [b,h,t,j] layout.
// =====================================================================
__global__ __launch_bounds__(256) void qkv_mfma(
    const float* __restrict__ seq,
    const float* __restrict__ Wq, const float* __restrict__ bq,
    const float* __restrict__ Wk, const float* __restrict__ bk,
    const float* __restrict__ Wv, const float* __restrict__ bv,
    __bf16* __restrict__ Qh, __bf16* __restrict__ Kh, __bf16* __restrict__ Vh,
    float* __restrict__ stats)
{
    __shared__ __bf16 As[64][264];      // [t][c], pad 264 (stride 528B -> 2-way banks)
    __shared__ __bf16 Ws[3][64][40];    // [p][co][c-chunk], pad 40 (80B -> 2-way)

    const int tid = threadIdx.x;
    const int t0  = blockIdx.x * 64;
    const int co0 = blockIdx.y * 64;
    const int bb  = blockIdx.z;

    // zero BN stats accumulators (one block; qkv dispatch completes before attn)
    if (blockIdx.x == 0 && blockIdx.y == 0 && bb == 0 && tid < 128)
        ((float4*)stats)[tid] = make_float4(0.f, 0.f, 0.f, 0.f);

    // ---- stage A = seq^T [64 t][256 c], f32 -> bf16 ----
    {
        const int cl = tid & 15;            // c within 16-chunk
        const int t4 = (tid >> 4) * 4;      // t base
        for (int it = 0; it < 16; ++it) {
            const int c = it*16 + cl;
            const float4 v = *(const float4*)&seq[((size_t)(bb*NC + c))*NT + t0 + t4];
            As[t4+0][c] = (__bf16)v.x;
            As[t4+1][c] = (__bf16)v.y;
            As[t4+2][c] = (__bf16)v.z;
            As[t4+3][c] = (__bf16)v.w;
        }
    }

    const float* Wp[3] = {Wq, Wk, Wv};

    f32x4 acc[3][4];
    #pragma unroll
    for (int p = 0; p < 3; ++p)
        #pragma unroll
        for (int n = 0; n < 4; ++n) acc[p][n] = (f32x4)0.f;

    const int l   = tid & 63;
    const int w   = tid >> 6;
    const int lr  = l & 15;
    const int lk8 = (l >> 4) * 8;

    // W-prefetch index map (constant across chunks): 6 float4 per thread
    int wp_[6], wco[6], wc4[6];
    #pragma unroll
    for (int i = 0; i < 6; ++i) {
        const int lin = i*256 + tid;        // 0..1535 float4s
        wp_[i] = lin >> 9;                  // proj
        const int r = lin & 511;
        wco[i] = r >> 3;
        wc4[i] = (r & 7) * 4;
    }

    float4 wreg[6];
    #pragma unroll
    for (int i = 0; i < 6; ++i)
        wreg[i] = *(const float4*)&Wp[wp_[i]][(size_t)(co0 + wco[i])*NC + wc4[i]];

    for (int kc = 0; kc < 8; ++kc) {
        __syncthreads();    // prior chunk's mfma done reading Ws
        #pragma unroll
        for (int i = 0; i < 6; ++i) {
            bf16x4 wb;
            wb[0] = (__bf16)wreg[i].x; wb[1] = (__bf16)wreg[i].y;
            wb[2] = (__bf16)wreg[i].z; wb[3] = (__bf16)wreg[i].w;
            *(bf16x4*)&Ws[wp_[i]][wco[i]][wc4[i]] = wb;
        }
        __syncthreads();

        if (kc < 7) {   // prefetch next chunk; latency hides under mfma below
            #pragma unroll
            for (int i = 0; i < 6; ++i)
                wreg[i] = *(const float4*)&Wp[wp_[i]][(size_t)(co0 + wco[i])*NC + (kc+1)*32 + wc4[i]];
        }

        const bf16x8 a = *(const bf16x8*)&As[w*16 + lr][kc*32 + lk8];
        #pragma unroll
        for (int p = 0; p < 3; ++p)
            #pragma unroll
            for (int n = 0; n < 4; ++n) {
                const bf16x8 bfr = *(const bf16x8*)&Ws[p][n*16 + lr][lk8];
                acc[p][n] = mfma16x16x32(a, bfr, acc[p][n]);
            }
    }

    // ---- epilogue: bias + relu (+SCALE for Q), bf16 store [b,h,t,j] ----
    const float* bias[3] = {bq, bk, bv};
    __bf16* outp[3] = {Qh, Kh, Vh};
    #pragma unroll
    for (int p = 0; p < 3; ++p) {
        #pragma unroll
        for (int n = 0; n < 4; ++n) {
            const int c  = co0 + n*16 + lr;
            const int hh = c >> 5, jj = c & 31;
            const float bv_ = bias[p][c];
            const float sc  = (p == 0) ? SCALE : 1.f;
            __bf16* op = outp[p] + ((size_t)(bb*NH + hh)*NT)*ND + jj;
            #pragma unroll
            for (int r = 0; r < 4; ++r) {
                const int t = t0 + w*16 + (l>>4)*4 + r;
                op[(size_t)t*ND] = (__bf16)(fmaxf(acc[p][n][r] + bv_, 0.f) * sc);
            }
        }
    }
}

// =====================================================================
// Kernel 2: flash attention, bf16 MFMA. Block = (b, h, 128 q-rows), 4 waves.
// Wave w owns rows [w*32, w*32+32). s-chunks of 64.
// QK^T: 1 mfma per 16x16 tile (K=32=ND). f32 Sb for exact -1e9 masking.
// P round-trips LDS as bf16 in A-frag layout; PV via mfma over V^T.
// Fused BN partial stats via atomics. Writes pre-BN x to out[b,c,t].
// =====================================================================
__global__ __launch_bounds__(256) void attn_mfma(
    const __bf16* __restrict__ Qh, const __bf16* __restrict__ Kh,
    const __bf16* __restrict__ Vh, const int* __restrict__ mask,
    float* __restrict__ xout, float* __restrict__ stats)
{
    __shared__ __bf16 Qs[128][40];    // [t][c]
    __shared__ __bf16 Ks[64][40];     // [s][c]
    __shared__ __bf16 VTs[32][72];    // [j][s]
    __shared__ float  Sb[128][68];    // [t][s] scores (f32, exact mask)
    __shared__ __bf16 PA[128][72];    // [t][s] probabilities bf16
    __shared__ int    smask[64];
    __shared__ float  rowf[128];
    __shared__ float  rowl[128];
    __shared__ float  bnsum[32][4];
    __shared__ float  bnsum2[32][4];

    const int tid = threadIdx.x;
    const int t0  = blockIdx.x * 128;
    const int h   = blockIdx.y;
    const int bb  = blockIdx.z;
    const int bh  = bb*NH + h;
    const __bf16* Qp = Qh + (size_t)bh*NT*ND;
    const __bf16* Kp = Kh + (size_t)bh*NT*ND;
    const __bf16* Vp = Vh + (size_t)bh*NT*ND;

    // ---- stage Q [128][32] bf16 (16B copies) ----
    #pragma unroll
    for (int it = 0; it < 2; ++it) {
        const int idx = it*256 + tid;
        const int t = idx >> 2, c8 = (idx & 3) * 8;
        *(uint4*)&Qs[t][c8] = *(const uint4*)&Qp[(size_t)(t0 + t)*ND + c8];
    }

    const int l   = tid & 63;
    const int w   = tid >> 6;
    const int lr  = l & 15;
    const int lk8 = (l >> 4) * 8;
    const int sm_row = tid >> 1, sm_li = tid & 1;

    f32x4 accO[2][2];
    #pragma unroll
    for (int tt = 0; tt < 2; ++tt)
        #pragma unroll
        for (int jt = 0; jt < 2; ++jt) accO[tt][jt] = (f32x4)0.f;
    float m_run = -1e30f, l_run = 0.f;

    const int kv_s = tid >> 2, kv_c8 = (tid & 3) * 8;   // K-staging map

    for (int s0 = 0; s0 < NT; s0 += 64) {
        // prefetch K, V, mask chunk into regs (before barrier: hides HBM/L2 latency)
        const uint4 kreg = *(const uint4*)&Kp[(size_t)(s0 + kv_s)*ND + kv_c8];
        ushort4 vreg[2];
        #pragma unroll
        for (int it = 0; it < 2; ++it) {
            const int lin = it*256 + tid;
            const int s = lin >> 3, j4 = (lin & 7) * 4;
            vreg[it] = *(const ushort4*)&Vp[(size_t)(s0 + s)*ND + j4];
        }
        const int mreg = (tid < 64) ? mask[bb*NT + s0 + tid] : 0;

        __syncthreads();   // prior chunk done reading Ks/VTs/PA/Sb
        *(uint4*)&Ks[kv_s][kv_c8] = kreg;
        #pragma unroll
        for (int it = 0; it < 2; ++it) {
            const int lin = it*256 + tid;
            const int s = lin >> 3, j4 = (lin & 7) * 4;
            const __bf16* vb = (const __bf16*)&vreg[it];
            VTs[j4+0][s] = vb[0]; VTs[j4+1][s] = vb[1];
            VTs[j4+2][s] = vb[2]; VTs[j4+3][s] = vb[3];
        }
        if (tid < 64) smask[tid] = mreg;
        __syncthreads();

        // ---- S = Q K^T (scale pre-folded into Q), exact -1e9 key mask ----
        {
            bf16x8 aq[2];
            aq[0] = *(const bf16x8*)&Qs[w*32      + lr][lk8];
            aq[1] = *(const bf16x8*)&Qs[w*32 + 16 + lr][lk8];
            #pragma unroll
            for (int n = 0; n < 4; ++n) {
                const bf16x8 bk_ = *(const bf16x8*)&Ks[n*16 + lr][lk8];
                const int km = smask[n*16 + lr];
                const int col = n*16 + lr;
                #pragma unroll
                for (int tt = 0; tt < 2; ++tt) {
                    const f32x4 s_ = mfma16x16x32(aq[tt], bk_, (f32x4)0.f);
                    const int row = w*32 + tt*16 + (l>>4)*4;
                    #pragma unroll
                    for (int r = 0; r < 4; ++r)
                        Sb[row + r][col] = km ? s_[r] : -1e9f;
                }
            }
        }
        __syncthreads();

        // ---- online softmax: 2 threads/row, 32 cols each; P -> bf16 PA ----
        {
            float vals[32];
            float mx = -1e30f;
            #pragma unroll
            for (int k4 = 0; k4 < 8; ++k4) {
                const float4 v = *(const float4*)&Sb[sm_row][sm_li*32 + k4*4];
                vals[k4*4+0] = v.x; vals[k4*4+1] = v.y;
                vals[k4*4+2] = v.z; vals[k4*4+3] = v.w;
                mx = fmaxf(mx, fmaxf(fmaxf(v.x, v.y), fmaxf(v.z, v.w)));
            }
            mx = fmaxf(mx, __shfl_xor(mx, 1));
            const float m_new = fmaxf(m_run, mx);
            const float f = __expf(m_run - m_new);
            float ssum = 0.f;
            #pragma unroll
            for (int k = 0; k < 32; ++k) {
                vals[k] = __expf(vals[k] - m_new);
                ssum += vals[k];
            }
            #pragma unroll
            for (int k4 = 0; k4 < 8; ++k4) {
                bf16x4 pb;
                pb[0] = (__bf16)vals[k4*4+0]; pb[1] = (__bf16)vals[k4*4+1];
                pb[2] = (__bf16)vals[k4*4+2]; pb[3] = (__bf16)vals[k4*4+3];
                *(bf16x4*)&PA[sm_row][sm_li*32 + k4*4] = pb;
            }
            ssum += __shfl_xor(ssum, 1);
            l_run = l_run*f + ssum;
            m_run = m_new;
            if (sm_li == 0) rowf[sm_row] = f;
        }
        __syncthreads();

        // ---- accO = accO*f + P @ V ----
        {
            float fr[2][4];
            #pragma unroll
            for (int tt = 0; tt < 2; ++tt)
                #pragma unroll
                for (int r = 0; r < 4; ++r)
                    fr[tt][r] = rowf[w*32 + tt*16 + (l>>4)*4 + r];
            #pragma unroll
            for (int tt = 0; tt < 2; ++tt)
                #pragma unroll
                for (int jt = 0; jt < 2; ++jt)
                    #pragma unroll
                    for (int r = 0; r < 4; ++r)
                        accO[tt][jt][r] *= fr[tt][r];

            #pragma unroll
            for (int kh = 0; kh < 2; ++kh) {
                bf16x8 pa[2], vb[2];
                pa[0] = *(const bf16x8*)&PA[w*32      + lr][kh*32 + lk8];
                pa[1] = *(const bf16x8*)&PA[w*32 + 16 + lr][kh*32 + lk8];
                vb[0] = *(const bf16x8*)&VTs[     lr][kh*32 + lk8];
                vb[1] = *(const bf16x8*)&VTs[16 + lr][kh*32 + lk8];
                #pragma unroll
                for (int tt = 0; tt < 2; ++tt)
                    #pragma unroll
                    for (int jt = 0; jt < 2; ++jt)
                        accO[tt][jt] = mfma16x16x32(pa[tt], vb[jt], accO[tt][jt]);
            }
        }
    }

    // ---- epilogue: 1/l * qmask, store x[b,c,t]; fused BN partial stats ----
    if (sm_li == 0)
        rowl[sm_row] = mask[bb*NT + t0 + sm_row] ? (1.f / l_run) : 0.f;
    __syncthreads();

    float psum[2] = {0.f, 0.f}, psq[2] = {0.f, 0.f};
    #pragma unroll
    for (int tt = 0; tt < 2; ++tt) {
        const int rbase = w*32 + tt*16 + (l>>4)*4;
        float rl[4];
        #pragma unroll
        for (int r = 0; r < 4; ++r) rl[r] = rowl[rbase + r];
        #pragma unroll
        for (int jt = 0; jt < 2; ++jt) {
            const int c = h*ND + jt*16 + lr;
            float4 o;
            o.x = accO[tt][jt][0]*rl[0];
            o.y = accO[tt][jt][1]*rl[1];
            o.z = accO[tt][jt][2]*rl[2];
            o.w = accO[tt][jt][3]*rl[3];
            *(float4*)&xout[((size_t)(bb*NC + c))*NT + t0 + rbase] = o;
            psum[jt] += o.x + o.y + o.z + o.w;
            psq[jt]  += o.x*o.x + o.y*o.y + o.z*o.z + o.w*o.w;
        }
    }
    #pragma unroll
    for (int jt = 0; jt < 2; ++jt) {
        psum[jt] += __shfl_xor(psum[jt], 16);
        psum[jt] += __shfl_xor(psum[jt], 32);
        psq[jt]  += __shfl_xor(psq[jt], 16);
        psq[jt]  += __shfl_xor(psq[jt], 32);
    }
    if (l < 16) {
        bnsum [l     ][w] = psum[0];  bnsum2[l     ][w] = psq[0];
        bnsum [l + 16][w] = psum[1];  bnsum2[l + 16][w] = psq[1];
    }
    __syncthreads();
    if (tid < 32) {
        const float s  = bnsum [tid][0] + bnsum [tid][1] + bnsum [tid][2] + bnsum [tid][3];
        const float s2 = bnsum2[tid][0] + bnsum2[tid][1] + bnsum2[tid][2] + bnsum2[tid][3];
        atomicAdd(&stats[h*ND + tid], s);
        atomicAdd(&stats[NC + h*ND + tid], s2);
    }
}

// =====================================================================
// Kernel 3: BN normalize + affine + re-mask, in place on d_out.
// Computes mean/rstd from the atomic sums inline.
// =====================================================================
__global__ __launch_bounds__(256) void bn_apply_kernel(
    float* __restrict__ x, const float* __restrict__ stats,
    const float* __restrict__ gamma, const float* __restrict__ beta,
    const int* __restrict__ mask)
{
    const int idx = blockIdx.x*256 + threadIdx.x;   // float4 index
    const int t4 = idx & 127;
    const int c  = (idx >> 7) & 255;
    const int bb = idx >> 15;
    float4 v = ((const float4*)x)[idx];
    const int4 mk = *(const int4*)&mask[bb*NT + t4*4];
    const float mean = stats[c] * (1.f/16384.f);
    const float var  = fmaxf(stats[NC + c]*(1.f/16384.f) - mean*mean, 0.f);
    const float rstd = rsqrtf(var + 1e-5f);
    const float g = gamma[c], be = beta[c];
    v.x = mk.x ? fmaf((v.x - mean)*rstd, g, be) : 0.f;
    v.y = mk.y ? fmaf((v.y - mean)*rstd, g, be) : 0.f;
    v.z = mk.z ? fmaf((v.z - mean)*rstd, g, be) : 0.f;
    v.w = mk.w ? fmaf((v.w - mean)*rstd, g, be) : 0.f;
    ((float4*)x)[idx] = v;
}

extern "C" void kernel_launch(void* const* d_in, const int* in_sizes, int n_in,
                              void* d_out, int out_size, void* d_ws, size_t ws_size,
                              hipStream_t stream)
{
    const float* seq   = (const float*)d_in[0];
    const int*   mask  = (const int*)  d_in[1];
    const float* Wq    = (const float*)d_in[2];
    const float* bq    = (const float*)d_in[3];
    const float* Wk    = (const float*)d_in[4];
    const float* bk    = (const float*)d_in[5];
    const float* Wv    = (const float*)d_in[6];
    const float* bv    = (const float*)d_in[7];
    const float* gamma = (const float*)d_in[8];
    const float* beta  = (const float*)d_in[9];
    float* out = (float*)d_out;

    const size_t perMat = (size_t)NB*NH*NT*ND;   // 4,194,304 elements
    __bf16* Qh = (__bf16*)d_ws;
    __bf16* Kh = Qh + perMat;
    __bf16* Vh = Kh + perMat;
    float* stats = (float*)(Vh + perMat);        // 512 floats (sum, sumsq)

    qkv_mfma<<<dim3(NT/64, NC/64, NB), 256, 0, stream>>>(
        seq, Wq, bq, Wk, bk, Wv, bv, Qh, Kh, Vh, stats);
    attn_mfma<<<dim3(NT/128, NH, NB), 256, 0, stream>>>(
        Qh, Kh, Vh, mask, out, stats);
    bn_apply_kernel<<<dim3((NB*NC*NT/4)/256), 256, 0, stream>>>(
        out, stats, gamma, beta, mask);
}

// Round 4
// 156.227 us; speedup vs baseline: 2.5543x; 1.0070x over previous
//
#include <hip/hip_runtime.h>
#include <math.h>

#define NB 32     // batch
#define NC 256    // channels
#define NT 512    // time
#define NH 8      // heads
#define ND 32     // head dim
#define SCALE 0.17677669529663687f            // 1/sqrt(32)
#define LOG2E 1.4426950408889634f
#define QSCALE (SCALE * LOG2E)                // folded into Q at qkv epilogue
#define MASKVAL (-1.4426950408889634e9f)      // -1e9 * log2e (base-2 domain)

typedef __attribute__((ext_vector_type(8))) __bf16 bf16x8;
typedef __attribute__((ext_vector_type(4))) __bf16 bf16x4;
typedef __attribute__((ext_vector_type(4))) float  f32x4;

static __device__ __forceinline__ f32x4 mfma16x16x32(bf16x8 a, bf16x8 b, f32x4 c) {
    return __builtin_amdgcn_mfma_f32_16x16x32_bf16(a, b, c, 0, 0, 0);
}

// =====================================================================
// Kernel 1: fused QKV projection via bf16 MFMA (unchanged structure).
// Q is pre-scaled by 1/sqrt(d) * log2(e) for base-2 softmax downstream.
// =====================================================================
__global__ __launch_bounds__(256) void qkv_mfma(
    const float* __restrict__ seq,
    const float* __restrict__ Wq, const float* __restrict__ bq,
    const float* __restrict__ Wk, const float* __restrict__ bk,
    const float* __restrict__ Wv, const float* __restrict__ bv,
    __bf16* __restrict__ Qh, __bf16* __restrict__ Kh, __bf16* __restrict__ Vh,
    float* __restrict__ stats)
{
    __shared__ __bf16 As[64][264];      // [t][c]
    __shared__ __bf16 Ws[3][64][40];    // [p][co][c-chunk]

    const int tid = threadIdx.x;
    const int t0  = blockIdx.x * 64;
    const int co0 = blockIdx.y * 64;
    const int bb  = blockIdx.z;

    if (blockIdx.x == 0 && blockIdx.y == 0 && bb == 0 && tid < 128)
        ((float4*)stats)[tid] = make_float4(0.f, 0.f, 0.f, 0.f);

    {
        const int cl = tid & 15;
        const int t4 = (tid >> 4) * 4;
        for (int it = 0; it < 16; ++it) {
            const int c = it*16 + cl;
            const float4 v = *(const float4*)&seq[((size_t)(bb*NC + c))*NT + t0 + t4];
            As[t4+0][c] = (__bf16)v.x;
            As[t4+1][c] = (__bf16)v.y;
            As[t4+2][c] = (__bf16)v.z;
            As[t4+3][c] = (__bf16)v.w;
        }
    }

    const float* Wp[3] = {Wq, Wk, Wv};

    f32x4 acc[3][4];
    #pragma unroll
    for (int p = 0; p < 3; ++p)
        #pragma unroll
        for (int n = 0; n < 4; ++n) acc[p][n] = (f32x4)0.f;

    const int l   = tid & 63;
    const int w   = tid >> 6;
    const int lr  = l & 15;
    const int lk8 = (l >> 4) * 8;

    int wp_[6], wco[6], wc4[6];
    #pragma unroll
    for (int i = 0; i < 6; ++i) {
        const int lin = i*256 + tid;
        wp_[i] = lin >> 9;
        const int r = lin & 511;
        wco[i] = r >> 3;
        wc4[i] = (r & 7) * 4;
    }

    float4 wreg[6];
    #pragma unroll
    for (int i = 0; i < 6; ++i)
        wreg[i] = *(const float4*)&Wp[wp_[i]][(size_t)(co0 + wco[i])*NC + wc4[i]];

    for (int kc = 0; kc < 8; ++kc) {
        __syncthreads();
        #pragma unroll
        for (int i = 0; i < 6; ++i) {
            bf16x4 wb;
            wb[0] = (__bf16)wreg[i].x; wb[1] = (__bf16)wreg[i].y;
            wb[2] = (__bf16)wreg[i].z; wb[3] = (__bf16)wreg[i].w;
            *(bf16x4*)&Ws[wp_[i]][wco[i]][wc4[i]] = wb;
        }
        __syncthreads();

        if (kc < 7) {
            #pragma unroll
            for (int i = 0; i < 6; ++i)
                wreg[i] = *(const float4*)&Wp[wp_[i]][(size_t)(co0 + wco[i])*NC + (kc+1)*32 + wc4[i]];
        }

        const bf16x8 a = *(const bf16x8*)&As[w*16 + lr][kc*32 + lk8];
        #pragma unroll
        for (int p = 0; p < 3; ++p)
            #pragma unroll
            for (int n = 0; n < 4; ++n) {
                const bf16x8 bfr = *(const bf16x8*)&Ws[p][n*16 + lr][lk8];
                acc[p][n] = mfma16x16x32(a, bfr, acc[p][n]);
            }
    }

    const float* bias[3] = {bq, bk, bv};
    __bf16* outp[3] = {Qh, Kh, Vh};
    #pragma unroll
    for (int p = 0; p < 3; ++p) {
        #pragma unroll
        for (int n = 0; n < 4; ++n) {
            const int c  = co0 + n*16 + lr;
            const int hh = c >> 5, jj = c & 31;
            const float bv_ = bias[p][c];
            const float sc  = (p == 0) ? QSCALE : 1.f;
            __bf16* op = outp[p] + ((size_t)(bb*NH + hh)*NT)*ND + jj;
            #pragma unroll
            for (int r = 0; r < 4; ++r) {
                const int t = t0 + w*16 + (l>>4)*4 + r;
                op[(size_t)t*ND] = (__bf16)(fmaxf(acc[p][n][r] + bv_, 0.f) * sc);
            }
        }
    }
}

// =====================================================================
// Kernel 2: flash attention, swapped-operand MFMA + in-register softmax.
// Block = (b, h, 128 q-rows), 4 waves; wave w owns q-rows [w*32, w*32+32).
// S^T = mfma(K, Q): lane holds S^T[s=st*16+4g+r][t=w*32+ct*16+(l&15)].
// Key mask via one __ballot word; row reduce via shfl_xor(16/32).
// P -> bf16 PA[t][s] (wave-private rows, no barrier); O^T = mfma(V^T, P^T).
// 2 barriers/chunk. Fused BN partial stats. Writes pre-BN x to out[b,c,t].
// =====================================================================
__global__ __launch_bounds__(256) void attn_mfma(
    const __bf16* __restrict__ Qh, const __bf16* __restrict__ Kh,
    const __bf16* __restrict__ Vh, const int* __restrict__ mask,
    float* __restrict__ xout, float* __restrict__ stats)
{
    __shared__ __bf16 Ks[64][40];     // [s][c]
    __shared__ __bf16 VTs[32][72];    // [j][s]
    __shared__ __bf16 PA[128][72];    // [t][s] probabilities bf16 (wave-private rows)
    __shared__ float  bnsum[32][4];
    __shared__ float  bnsum2[32][4];

    const int tid = threadIdx.x;
    const int t0  = blockIdx.x * 128;
    const int h   = blockIdx.y;
    const int bb  = blockIdx.z;
    const int bh  = bb*NH + h;
    const __bf16* Qp = Qh + (size_t)bh*NT*ND;
    const __bf16* Kp = Kh + (size_t)bh*NT*ND;
    const __bf16* Vp = Vh + (size_t)bh*NT*ND;

    const int l   = tid & 63;
    const int w   = tid >> 6;
    const int lr  = l & 15;
    const int g   = l >> 4;
    const int lk8 = g * 8;

    // Q B-fragments: constant for whole kernel, keep in registers.
    bf16x8 qb[2];
    #pragma unroll
    for (int ct = 0; ct < 2; ++ct)
        qb[ct] = *(const bf16x8*)&Qp[(size_t)(t0 + w*32 + ct*16 + lr)*ND + lk8];

    f32x4 accO[2][2];   // [jt][ct]: O^T[j=jt*16+4g+r][t=w*32+ct*16+lr]
    #pragma unroll
    for (int jt = 0; jt < 2; ++jt)
        #pragma unroll
        for (int ct = 0; ct < 2; ++ct) accO[jt][ct] = (f32x4)0.f;
    float m_run[2] = {-1e30f, -1e30f};
    float l_run[2] = {0.f, 0.f};

    const int kv_s = tid >> 2, kv_c8 = (tid & 3) * 8;

    for (int s0 = 0; s0 < NT; s0 += 64) {
        // prefetch K, V into regs; key-mask chunk as a ballot word
        const uint4 kreg = *(const uint4*)&Kp[(size_t)(s0 + kv_s)*ND + kv_c8];
        ushort4 vreg[2];
        #pragma unroll
        for (int it = 0; it < 2; ++it) {
            const int lin = it*256 + tid;
            const int s = lin >> 3, j4 = (lin & 7) * 4;
            vreg[it] = *(const ushort4*)&Vp[(size_t)(s0 + s)*ND + j4];
        }
        const unsigned long long mw = __ballot(mask[bb*NT + s0 + l] != 0);

        __syncthreads();   // prior chunk done reading Ks/VTs
        *(uint4*)&Ks[kv_s][kv_c8] = kreg;
        #pragma unroll
        for (int it = 0; it < 2; ++it) {
            const int lin = it*256 + tid;
            const int s = lin >> 3, j4 = (lin & 7) * 4;
            const __bf16* vb = (const __bf16*)&vreg[it];
            VTs[j4+0][s] = vb[0]; VTs[j4+1][s] = vb[1];
            VTs[j4+2][s] = vb[2]; VTs[j4+3][s] = vb[3];
        }
        __syncthreads();

        // K A-fragments for this chunk (shared by both ct)
        bf16x8 kA[4];
        #pragma unroll
        for (int st = 0; st < 4; ++st)
            kA[st] = *(const bf16x8*)&Ks[st*16 + lr][lk8];

        #pragma unroll
        for (int ct = 0; ct < 2; ++ct) {
            // S^T tiles: lane gets s = st*16 + 4g + r for q-row t
            f32x4 sst[4];
            #pragma unroll
            for (int st = 0; st < 4; ++st)
                sst[st] = mfma16x16x32(kA[st], qb[ct], (f32x4)0.f);

            // key mask + row max (in-register, then 4-lane-group shfl)
            float v[16];
            float mx = -1e30f;
            #pragma unroll
            for (int st = 0; st < 4; ++st)
                #pragma unroll
                for (int r = 0; r < 4; ++r) {
                    const int s = st*16 + g*4 + r;
                    const float val = ((mw >> s) & 1ull) ? sst[st][r] : MASKVAL;
                    v[st*4+r] = val;
                    mx = fmaxf(mx, val);
                }
            mx = fmaxf(mx, __shfl_xor(mx, 16));
            mx = fmaxf(mx, __shfl_xor(mx, 32));
            const float m_new = fmaxf(m_run[ct], mx);
            const float f = exp2f(m_run[ct] - m_new);

            // exp2, partial sum, write P (bf16) into wave-private PA rows
            const int trow = w*32 + ct*16 + lr;
            float ssum = 0.f;
            #pragma unroll
            for (int st = 0; st < 4; ++st) {
                bf16x4 pb4;
                #pragma unroll
                for (int r = 0; r < 4; ++r) {
                    const float p = exp2f(v[st*4+r] - m_new);
                    ssum += p;
                    pb4[r] = (__bf16)p;
                }
                *(bf16x4*)&PA[trow][st*16 + g*4] = pb4;
            }
            ssum += __shfl_xor(ssum, 16);
            ssum += __shfl_xor(ssum, 32);
            l_run[ct] = l_run[ct]*f + ssum;
            m_run[ct] = m_new;

            #pragma unroll
            for (int jt = 0; jt < 2; ++jt)
                #pragma unroll
                for (int r = 0; r < 4; ++r)
                    accO[jt][ct][r] *= f;
        }

        // PV: O^T += V^T @ P^T  (PA rows are wave-private; in-order DS suffices)
        #pragma unroll
        for (int kh = 0; kh < 2; ++kh) {
            bf16x8 va[2], pb[2];
            #pragma unroll
            for (int jt = 0; jt < 2; ++jt)
                va[jt] = *(const bf16x8*)&VTs[jt*16 + lr][kh*32 + lk8];
            #pragma unroll
            for (int ct = 0; ct < 2; ++ct)
                pb[ct] = *(const bf16x8*)&PA[w*32 + ct*16 + lr][kh*32 + lk8];
            #pragma unroll
            for (int jt = 0; jt < 2; ++jt)
                #pragma unroll
                for (int ct = 0; ct < 2; ++ct)
                    accO[jt][ct] = mfma16x16x32(va[jt], pb[ct], accO[jt][ct]);
        }
    }

    // ---- epilogue: 1/l * qmask, store x[b,c,t] (O^T layout); BN partials ----
    float psum[2][4], psq[2][4];
    #pragma unroll
    for (int jt = 0; jt < 2; ++jt)
        #pragma unroll
        for (int r = 0; r < 4; ++r) { psum[jt][r] = 0.f; psq[jt][r] = 0.f; }

    #pragma unroll
    for (int ct = 0; ct < 2; ++ct) {
        const int t = t0 + w*32 + ct*16 + lr;
        const float rl = mask[bb*NT + t] ? (1.f / l_run[ct]) : 0.f;
        #pragma unroll
        for (int jt = 0; jt < 2; ++jt) {
            #pragma unroll
            for (int r = 0; r < 4; ++r) {
                const int c = h*ND + jt*16 + g*4 + r;
                const float o = accO[jt][ct][r] * rl;
                xout[((size_t)(bb*NC + c))*NT + t] = o;
                psum[jt][r] += o;
                psq[jt][r]  += o*o;
            }
        }
    }
    // reduce over the 16 t-lanes
    #pragma unroll
    for (int jt = 0; jt < 2; ++jt)
        #pragma unroll
        for (int r = 0; r < 4; ++r) {
            #pragma unroll
            for (int off = 1; off < 16; off <<= 1) {
                psum[jt][r] += __shfl_xor(psum[jt][r], off);
                psq[jt][r]  += __shfl_xor(psq[jt][r],  off);
            }
        }
    if (lr == 0) {
        #pragma unroll
        for (int jt = 0; jt < 2; ++jt)
            #pragma unroll
            for (int r = 0; r < 4; ++r) {
                bnsum [jt*16 + g*4 + r][w] = psum[jt][r];
                bnsum2[jt*16 + g*4 + r][w] = psq[jt][r];
            }
    }
    __syncthreads();
    if (tid < 32) {
        const float s  = bnsum [tid][0] + bnsum [tid][1] + bnsum [tid][2] + bnsum [tid][3];
        const float s2 = bnsum2[tid][0] + bnsum2[tid][1] + bnsum2[tid][2] + bnsum2[tid][3];
        atomicAdd(&stats[h*ND + tid], s);
        atomicAdd(&stats[NC + h*ND + tid], s2);
    }
}

// =====================================================================
// Kernel 3: BN normalize + affine + re-mask, in place on d_out.
// =====================================================================
__global__ __launch_bounds__(256) void bn_apply_kernel(
    float* __restrict__ x, const float* __restrict__ stats,
    const float* __restrict__ gamma, const float* __restrict__ beta,
    const int* __restrict__ mask)
{
    const int idx = blockIdx.x*256 + threadIdx.x;
    const int t4 = idx & 127;
    const int c  = (idx >> 7) & 255;
    const int bb = idx >> 15;
    float4 v = ((const float4*)x)[idx];
    const int4 mk = *(const int4*)&mask[bb*NT + t4*4];
    const float mean = stats[c] * (1.f/16384.f);
    const float var  = fmaxf(stats[NC + c]*(1.f/16384.f) - mean*mean, 0.f);
    const float rstd = rsqrtf(var + 1e-5f);
    const float g = gamma[c], be = beta[c];
    v.x = mk.x ? fmaf((v.x - mean)*rstd, g, be) : 0.f;
    v.y = mk.y ? fmaf((v.y - mean)*rstd, g, be) : 0.f;
    v.z = mk.z ? fmaf((v.z - mean)*rstd, g, be) : 0.f;
    v.w = mk.w ? fmaf((v.w - mean)*rstd, g, be) : 0.f;
    ((float4*)x)[idx] = v;
}

extern "C" void kernel_launch(void* const* d_in, const int* in_sizes, int n_in,
                              void* d_out, int out_size, void* d_ws, size_t ws_size,
                              hipStream_t stream)
{
    const float* seq   = (const float*)d_in[0];
    const int*   mask  = (const int*)  d_in[1];
    const float* Wq    = (const float*)d_in[2];
    const float* bq    = (const float*)d_in[3];
    const float* Wk    = (const float*)d_in[4];
    const float* bk    = (const float*)d_in[5];
    const float* Wv    = (const float*)d_in[6];
    const float* bv    = (const float*)d_in[7];
    const float* gamma = (const float*)d_in[8];
    const float* beta  = (const float*)d_in[9];
    float* out = (float*)d_out;

    const size_t perMat = (size_t)NB*NH*NT*ND;
    __bf16* Qh = (__bf16*)d_ws;
    __bf16* Kh = Qh + perMat;
    __bf16* Vh = Kh + perMat;
    float* stats = (float*)(Vh + perMat);

    qkv_mfma<<<dim3(NT/64, NC/64, NB), 256, 0, stream>>>(
        seq, Wq, bq, Wk, bk, Wv, bv, Qh, Kh, Vh, stats);
    attn_mfma<<<dim3(NT/128, NH, NB), 256, 0, stream>>>(
        Qh, Kh, Vh, mask, out, stats);
    bn_apply_kernel<<<dim3((NB*NC*NT/4)/256), 256, 0, stream>>>(
        out, stats, gamma, beta, mask);
}